// Round 1
// baseline (438.709 us; speedup 1.0000x reference)
//
#include <hip/hip_runtime.h>
#include <hip/hip_bf16.h>
#include <math.h>

// Problem constants (fixed by reference setup)
#define D_DIM   2048
#define NE      64
#define NTOK    16384      // B*T = 4*4096
#define TK      8
#define TPB     256
#define TOKB    64         // tokens per block (= lanes per wave)
#define KC      128        // K-chunk staged in LDS
#define XS      129        // padded LDS row stride (conflict-free: bank = (lane+d)%32)

// out layout: [weights 131072][indices-as-float 131072][scores 1048576]
#define OUT_I_OFF (NTOK * TK)
#define OUT_S_OFF (2 * NTOK * TK)

__global__ __launch_bounds__(TPB) void gate_kernel(
    const float* __restrict__ x, const float* __restrict__ w,
    const float* __restrict__ gb, float* __restrict__ out)
{
    __shared__ float xs[TOKB * XS];        // 33 KB: x chunk, [token][d] padded
    __shared__ float ss[TOKB * (NE + 1)];  // 16.6 KB: scores, [token][expert] padded

    const int tid  = threadIdx.x;
    const int lane = tid & 63;
    const int wid  = __builtin_amdgcn_readfirstlane(tid >> 6);  // force SGPR -> s_load for w
    const int tok0 = blockIdx.x * TOKB;
    const int e0   = wid * 16;

    float acc[16];
#pragma unroll
    for (int i = 0; i < 16; ++i) acc[i] = 0.f;

    // ---- register prefetch of chunk 0 (64 tokens x 128 floats = 2048 float4, 8/thread)
    float4 pf[8];
#pragma unroll
    for (int r = 0; r < 8; ++r) {
        int idx = r * TPB + tid;
        int t   = idx >> 5;          // 32 float4 per token row
        int c   = idx & 31;
        pf[r] = *(const float4*)(x + (size_t)(tok0 + t) * D_DIM + c * 4);
    }

    for (int k0 = 0; k0 < D_DIM; k0 += KC) {
        __syncthreads();   // previous chunk's compute reads done before overwrite
#pragma unroll
        for (int r = 0; r < 8; ++r) {
            int idx = r * TPB + tid;
            int t   = idx >> 5;
            int c   = idx & 31;
            float* dst = &xs[t * XS + c * 4];
            dst[0] = pf[r].x; dst[1] = pf[r].y; dst[2] = pf[r].z; dst[3] = pf[r].w;
        }
        __syncthreads();

        // issue next chunk's global loads now; compiler waits (vmcnt) only at next LDS write
        if (k0 + KC < D_DIM) {
#pragma unroll
            for (int r = 0; r < 8; ++r) {
                int idx = r * TPB + tid;
                int t   = idx >> 5;
                int c   = idx & 31;
                pf[r] = *(const float4*)(x + (size_t)(tok0 + t) * D_DIM + (k0 + KC) + c * 4);
            }
        }

        // ---- compute: lane = token, wave's 16 experts via scalar (SGPR) w loads
        const float* wp   = w + (size_t)e0 * D_DIM + k0;   // wave-uniform
        const float* xrow = &xs[lane * XS];
#pragma unroll 4
        for (int d = 0; d < KC; ++d) {
            float xv = xrow[d];
#pragma unroll
            for (int e = 0; e < 16; ++e) {
                acc[e] = fmaf(xv, wp[(size_t)e * D_DIM + d], acc[e]);
            }
        }
    }

    // ---- epilogue: sigmoid + bias, write scores (global + LDS)
    float sc[16];
#pragma unroll
    for (int e = 0; e < 16; ++e) {
        sc[e] = 1.f / (1.f + expf(-acc[e])) + gb[e0 + e];
    }
    {
        float* outs = out + OUT_S_OFF + (size_t)(tok0 + lane) * NE + e0;
        float4 v0 = {sc[0],  sc[1],  sc[2],  sc[3]};
        float4 v1 = {sc[4],  sc[5],  sc[6],  sc[7]};
        float4 v2 = {sc[8],  sc[9],  sc[10], sc[11]};
        float4 v3 = {sc[12], sc[13], sc[14], sc[15]};
        ((float4*)outs)[0] = v0; ((float4*)outs)[1] = v1;
        ((float4*)outs)[2] = v2; ((float4*)outs)[3] = v3;
    }
#pragma unroll
    for (int e = 0; e < 16; ++e) ss[lane * (NE + 1) + e0 + e] = sc[e];
    __syncthreads();

    // ---- fused top-8: 4 lanes per token, 16 scores each, in registers
    const int t = tid >> 2;    // token 0..63
    const int q = tid & 3;     // quarter
    float v[16];
#pragma unroll
    for (int j = 0; j < 16; ++j) v[j] = ss[t * (NE + 1) + q * 16 + j];

    float kv[TK]; int ki[TK];
#pragma unroll
    for (int k = 0; k < TK; ++k) {
        // local argmax (ascending scan, strict > => first occurrence = lowest index)
        float bv = v[0]; int bi = q * 16;
#pragma unroll
        for (int j = 1; j < 16; ++j) {
            bool gt = v[j] > bv;
            bv = gt ? v[j] : bv;
            bi = gt ? (q * 16 + j) : bi;
        }
        // width-4 butterfly; ties -> lower index (matches jax.lax.top_k stability)
#pragma unroll
        for (int off = 1; off < 4; off <<= 1) {
            float ov = __shfl_xor(bv, off);
            int   oi = __shfl_xor(bi, off);
            bool take = (ov > bv) || (ov == bv && oi < bi);
            bv = take ? ov : bv;
            bi = take ? oi : bi;
        }
        // clear the winner in its owner's registers
        int lj = bi - q * 16;
#pragma unroll
        for (int j = 0; j < 16; ++j) v[j] = (j == lj) ? -3e38f : v[j];
        kv[k] = bv; ki[k] = bi;
    }

    if (q == 0) {
        float s = 0.f;
#pragma unroll
        for (int k = 0; k < TK; ++k) s += kv[k];
        float inv = 1.f / s;
        float* ow = out + (size_t)(tok0 + t) * TK;
        float* oi = out + OUT_I_OFF + (size_t)(tok0 + t) * TK;
#pragma unroll
        for (int k = 0; k < TK; ++k) {
            ow[k] = kv[k] * inv;
            oi[k] = (float)ki[k];
        }
    }
}

extern "C" void kernel_launch(void* const* d_in, const int* in_sizes, int n_in,
                              void* d_out, int out_size, void* d_ws, size_t ws_size,
                              hipStream_t stream) {
    const float* x  = (const float*)d_in[0];   // [4,4096,2048]
    const float* w  = (const float*)d_in[1];   // [64,2048]
    const float* gb = (const float*)d_in[2];   // [64]
    // d_in[3] = top_k scalar; fixed at 8 per reference setup
    float* out = (float*)d_out;
    (void)in_sizes; (void)n_in; (void)out_size; (void)d_ws; (void)ws_size;

    dim3 grid(NTOK / TOKB);   // 256 blocks
    dim3 block(TPB);          // 256 threads = 4 waves
    gate_kernel<<<grid, block, 0, stream>>>(x, w, gb, out);
}

// Round 2
// 417.397 us; speedup vs baseline: 1.0511x; 1.0511x over previous
//
#include <hip/hip_runtime.h>
#include <math.h>

#define D_DIM 2048
#define NE    64
#define NTOK  16384
#define TK    8
#define KC    128            // d-chunk staged in LDS
#define GT    512            // gemm block threads (8 waves)
#define TOKB  64             // tokens per gemm block
#define NCHUNK (D_DIM / KC)  // 16

#define OUT_I_OFF (NTOK * TK)
#define OUT_S_OFF (2 * NTOK * TK)

#define GLOBAL_AS __attribute__((address_space(1)))
#define LDS_AS    __attribute__((address_space(3)))

static __device__ __forceinline__ void async_copy16(const float* g, float* l) {
    __builtin_amdgcn_global_load_lds((const GLOBAL_AS void*)g, (LDS_AS void*)l, 16, 0, 0);
}

// ---------- kernel 0: w[e][d] -> wT[d][e] in workspace (coalesced writes) ----------
__global__ __launch_bounds__(256) void wtrans_kernel(const float* __restrict__ w,
                                                     float* __restrict__ wt) {
    const int b = blockIdx.x;
#pragma unroll
    for (int rep = 0; rep < 4; ++rep) {
        int idx = b * 1024 + rep * 256 + threadIdx.x;   // 128 blocks * 1024 = 131072
        int d = idx >> 6, e = idx & 63;
        wt[idx] = w[(size_t)e * D_DIM + d];
    }
}

// ---------- kernel 1: scores = sigmoid(x . w^T) + gb, written to out[scores] ----------
// lane = token (64/block), wave = 8 experts; w via SGPR (uniform) with wA/wB pipeline;
// x staged by global_load_lds with XOR-swizzled 16B quads for conflict-free ds_read_b128.
template <bool USE_WT>
__global__ __launch_bounds__(GT) void gate_gemm(const float* __restrict__ x,
                                                const float* __restrict__ w,
                                                const float* __restrict__ wt,
                                                const float* __restrict__ gb,
                                                float* __restrict__ scores) {
    __shared__ float xs[2][TOKB * KC];   // 2 x 32 KB

    const int tid  = threadIdx.x;
    const int lane = tid & 63;           // token within block
    const int wid  = tid >> 6;           // 0..7
    const int e0   = wid * 8;            // this wave's experts
    const int tok0 = blockIdx.x * TOKB;
    const int t7   = lane & 7;           // read-side XOR swizzle key

    float acc[8];
#pragma unroll
    for (int e = 0; e < 8; ++e) acc[e] = 0.f;

    // stage one KC-chunk into xs[buf]; slot s holds quad (t = s>>5, dq = (s&31)^(t&7))
    auto stage = [&](int c, int buf) {
#pragma unroll
        for (int r = 0; r < 4; ++r) {
            int s   = r * GT + tid;          // 0..2047 quad slots (2048*16B = 32 KB)
            int t   = s >> 5;                // 32 quads per token row
            int dq  = (s & 31) ^ (t & 7);    // logical quad stored at this slot
            const float* g = x + (size_t)(tok0 + t) * D_DIM + c * KC + (dq << 2);
            async_copy16(g, &xs[buf][s * 4]);
        }
    };

    // uniform w loads -> SGPRs (4 consecutive d, 8 consecutive experts)
    auto loadw = [&](float* dst, int d) {
        if (USE_WT) {
#pragma unroll
            for (int j = 0; j < 4; ++j)
#pragma unroll
                for (int e = 0; e < 8; ++e)
                    dst[j * 8 + e] = wt[(size_t)(d + j) * NE + e0 + e];
        } else {
#pragma unroll
            for (int e = 0; e < 8; ++e)
#pragma unroll
                for (int j = 0; j < 4; ++j)
                    dst[j * 8 + e] = w[(size_t)(e0 + e) * D_DIM + d + j];
        }
    };

    float wA[32], wB[32];
    loadw(wA, 0);
    stage(0, 0);

    for (int c = 0; c < NCHUNK; ++c) {
        __syncthreads();                       // drains chunk-c loads (vmcnt@barrier)
        if (c + 1 < NCHUNK) stage(c + 1, (c + 1) & 1);
        const float* xrow = &xs[c & 1][lane * KC];
        const int d0 = c * KC;

        for (int dd = 0; dd < KC; dd += 8) {
            // phase A: prefetch wB(d+4), compute with wA(d)
            loadw(wB, (d0 + dd + 4) & (D_DIM - 1));
            {
                int dq = dd >> 2;
                float4 xq = *(const float4*)(xrow + ((dq ^ t7) << 2));
#pragma unroll
                for (int e = 0; e < 8; ++e) acc[e] = fmaf(xq.x, wA[0 * 8 + e], acc[e]);
#pragma unroll
                for (int e = 0; e < 8; ++e) acc[e] = fmaf(xq.y, wA[1 * 8 + e], acc[e]);
#pragma unroll
                for (int e = 0; e < 8; ++e) acc[e] = fmaf(xq.z, wA[2 * 8 + e], acc[e]);
#pragma unroll
                for (int e = 0; e < 8; ++e) acc[e] = fmaf(xq.w, wA[3 * 8 + e], acc[e]);
            }
            // phase B: prefetch wA(d+8), compute with wB(d+4)
            loadw(wA, (d0 + dd + 8) & (D_DIM - 1));
            {
                int dq = (dd >> 2) + 1;
                float4 xq = *(const float4*)(xrow + ((dq ^ t7) << 2));
#pragma unroll
                for (int e = 0; e < 8; ++e) acc[e] = fmaf(xq.x, wB[0 * 8 + e], acc[e]);
#pragma unroll
                for (int e = 0; e < 8; ++e) acc[e] = fmaf(xq.y, wB[1 * 8 + e], acc[e]);
#pragma unroll
                for (int e = 0; e < 8; ++e) acc[e] = fmaf(xq.z, wB[2 * 8 + e], acc[e]);
#pragma unroll
                for (int e = 0; e < 8; ++e) acc[e] = fmaf(xq.w, wB[3 * 8 + e], acc[e]);
            }
        }
    }

    // epilogue: sigmoid + bias -> scores[t][e0..e0+7]
    float sc[8];
#pragma unroll
    for (int e = 0; e < 8; ++e) sc[e] = 1.f / (1.f + expf(-acc[e])) + gb[e0 + e];
    float* so = scores + (size_t)(tok0 + lane) * NE + e0;
    float4 v0 = {sc[0], sc[1], sc[2], sc[3]};
    float4 v1 = {sc[4], sc[5], sc[6], sc[7]};
    ((float4*)so)[0] = v0;
    ((float4*)so)[1] = v1;
}

// ---------- kernel 2: top-8 + normalize (R1-verified semantics) ----------
__global__ __launch_bounds__(256) void topk_kernel(const float* __restrict__ scores,
                                                   float* __restrict__ out) {
    const int tid = threadIdx.x;
    const int t   = blockIdx.x * 64 + (tid >> 2);  // global token
    const int q   = tid & 3;                       // quarter: 16 scores each
    float v[16];
    const float4* sp = (const float4*)(scores + (size_t)t * NE + q * 16);
    float4 a = sp[0], b = sp[1], c = sp[2], d = sp[3];
    v[0] = a.x;  v[1] = a.y;  v[2] = a.z;  v[3] = a.w;
    v[4] = b.x;  v[5] = b.y;  v[6] = b.z;  v[7] = b.w;
    v[8] = c.x;  v[9] = c.y;  v[10] = c.z; v[11] = c.w;
    v[12] = d.x; v[13] = d.y; v[14] = d.z; v[15] = d.w;

    float kv[TK]; int ki[TK];
#pragma unroll
    for (int k = 0; k < TK; ++k) {
        float bv = v[0]; int bi = q * 16;
#pragma unroll
        for (int j = 1; j < 16; ++j) {
            bool gt = v[j] > bv;
            bv = gt ? v[j] : bv;
            bi = gt ? (q * 16 + j) : bi;
        }
#pragma unroll
        for (int off = 1; off < 4; off <<= 1) {
            float ov = __shfl_xor(bv, off);
            int   oi = __shfl_xor(bi, off);
            bool take = (ov > bv) || (ov == bv && oi < bi);  // ties -> lower index
            bv = take ? ov : bv;
            bi = take ? oi : bi;
        }
        int lj = bi - q * 16;
#pragma unroll
        for (int j = 0; j < 16; ++j) v[j] = (j == lj) ? -3e38f : v[j];
        kv[k] = bv; ki[k] = bi;
    }

    if (q == 0) {
        float s = 0.f;
#pragma unroll
        for (int k = 0; k < TK; ++k) s += kv[k];
        float inv = 1.f / s;
        float* ow = out + (size_t)t * TK;
        float* oi = out + OUT_I_OFF + (size_t)t * TK;
#pragma unroll
        for (int k = 0; k < TK; ++k) {
            ow[k] = kv[k] * inv;
            oi[k] = (float)ki[k];
        }
    }
}

extern "C" void kernel_launch(void* const* d_in, const int* in_sizes, int n_in,
                              void* d_out, int out_size, void* d_ws, size_t ws_size,
                              hipStream_t stream) {
    const float* x  = (const float*)d_in[0];   // [4,4096,2048]
    const float* w  = (const float*)d_in[1];   // [64,2048]
    const float* gb = (const float*)d_in[2];   // [64]
    float* out    = (float*)d_out;
    float* scores = out + OUT_S_OFF;           // gemm writes output-3 in place
    float* wtbuf  = (float*)d_ws;
    (void)in_sizes; (void)n_in; (void)out_size;

    const bool use_wt = ws_size >= (size_t)NE * D_DIM * sizeof(float);
    if (use_wt) {
        wtrans_kernel<<<dim3(128), dim3(256), 0, stream>>>(w, wtbuf);
        gate_gemm<true><<<dim3(NTOK / TOKB), dim3(GT), 0, stream>>>(x, w, wtbuf, gb, scores);
    } else {
        gate_gemm<false><<<dim3(NTOK / TOKB), dim3(GT), 0, stream>>>(x, w, wtbuf, gb, scores);
    }
    topk_kernel<<<dim3(NTOK / 64), dim3(256), 0, stream>>>(scores, out);
}

// Round 3
// 285.709 us; speedup vs baseline: 1.5355x; 1.4609x over previous
//
#include <hip/hip_runtime.h>
#include <math.h>

#define D_DIM 2048
#define NE    64
#define NTOK  16384
#define TK    8
#define TOKB  64             // tokens per block
#define HALF  1024           // D/2 (2-way split-K per wave)
#define KCH   64             // d per half per chunk (128 d total per barrier)
#define NCH   (HALF / KCH)   // 16 chunks
#define GT    1024           // 16 waves/block

#define OUT_I_OFF (NTOK * TK)
#define OUT_S_OFF (2 * NTOK * TK)

#define GLOBAL_AS __attribute__((address_space(1)))
#define LDS_AS    __attribute__((address_space(3)))

static __device__ __forceinline__ void async_copy16(const float* g, float* l) {
    __builtin_amdgcn_global_load_lds((const GLOBAL_AS void*)g, (LDS_AS void*)l, 16, 0, 0);
}

// ---------- kernel 0: w[e][d] -> wT[d][e] (coalesced float4 reads) ----------
__global__ __launch_bounds__(256) void wtrans_kernel(const float* __restrict__ w,
                                                     float* __restrict__ wt) {
    int i = blockIdx.x * 256 + threadIdx.x;        // 32768 threads, one float4 each
    int e  = i >> 9;                                // 512 float4 per expert row
    int db = i & 511;
    float4 v = ((const float4*)w)[(size_t)e * 512 + db];
    int d = db * 4;
    wt[(size_t)(d + 0) * NE + e] = v.x;
    wt[(size_t)(d + 1) * NE + e] = v.y;
    wt[(size_t)(d + 2) * NE + e] = v.z;
    wt[(size_t)(d + 3) * NE + e] = v.w;
}

// ---------- kernel 1: scores = sigmoid(x.wT) + gb ----------
// 16 waves: wave = (expert-group g in 0..7, K-half h in 0..1); lane = token.
// x: global_load_lds staged, XOR-swizzled 16B quads (global-side swizzle, LDS dest
// is wave-uniform-base + lane*16 as required). w: wave-uniform SGPR loads, wA/wB pipelined.
template <bool USE_WT>
__global__ __launch_bounds__(GT) void gate_gemm(const float* __restrict__ x,
                                                const float* __restrict__ w,
                                                const float* __restrict__ wt,
                                                const float* __restrict__ gb,
                                                float* __restrict__ scores) {
    __shared__ float xs[2][2][TOKB * KCH];   // [buf][half][tok*64+d'] = 64 KB

    const int tid  = threadIdx.x;
    const int lane = tid & 63;                                   // token
    const int wv   = __builtin_amdgcn_readfirstlane(tid >> 6);   // 0..15, uniform
    const int g    = wv & 7;                                     // expert group
    const int h    = wv >> 3;                                    // K half
    const int e0   = g * 8;
    const int tok0 = blockIdx.x * TOKB;
    const int l7   = lane & 7;

    // staging map: thread t covers quad-slot s=t in each half; row st, slot-quad sq;
    // logical quad dq = sq ^ (st&7) (self-inverse swizzle, applied on the GLOBAL side)
    const int st = tid >> 4;
    const int sq = tid & 15;
    const int dq = sq ^ (st & 7);
    const float* gx = x + (size_t)(tok0 + st) * D_DIM + (dq << 2);

    auto stage = [&](int c, int buf) {
        async_copy16(gx + 0 * HALF + c * KCH, &xs[buf][0][tid * 4]);
        async_copy16(gx + 1 * HALF + c * KCH, &xs[buf][1][tid * 4]);
    };

    // wave-uniform w loads: 4 consecutive d (within this wave's half), 8 experts
    auto loadw = [&](float* dst, int hd) {
        if (USE_WT) {
            const float* p = wt + (size_t)(h * HALF + hd) * NE + e0;
#pragma unroll
            for (int j = 0; j < 4; ++j)
#pragma unroll
                for (int e = 0; e < 8; ++e) dst[j * 8 + e] = p[j * NE + e];
        } else {
#pragma unroll
            for (int e = 0; e < 8; ++e) {
                const float* p = w + (size_t)(e0 + e) * D_DIM + h * HALF + hd;
#pragma unroll
                for (int j = 0; j < 4; ++j) dst[j * 8 + e] = p[j];
            }
        }
    };

    float acc[8];
#pragma unroll
    for (int e = 0; e < 8; ++e) acc[e] = 0.f;

    float wA[32], wB[32];
    loadw(wA, 0);
    stage(0, 0);

    for (int c = 0; c < NCH; ++c) {
        __syncthreads();                       // drains chunk-c staging (vmcnt@barrier)
        if (c + 1 < NCH) stage(c + 1, (c + 1) & 1);
        const float* xrow = &xs[c & 1][h][lane * KCH];

        for (int dd = 0; dd < KCH; dd += 8) {
            const int hd = c * KCH + dd;
            loadw(wB, (hd + 4) & (HALF - 1));
            {
                float4 xq = *(const float4*)(xrow + ((((dd >> 2) + 0) ^ l7) << 2));
#pragma unroll
                for (int e = 0; e < 8; ++e) acc[e] = fmaf(xq.x, wA[0 * 8 + e], acc[e]);
#pragma unroll
                for (int e = 0; e < 8; ++e) acc[e] = fmaf(xq.y, wA[1 * 8 + e], acc[e]);
#pragma unroll
                for (int e = 0; e < 8; ++e) acc[e] = fmaf(xq.z, wA[2 * 8 + e], acc[e]);
#pragma unroll
                for (int e = 0; e < 8; ++e) acc[e] = fmaf(xq.w, wA[3 * 8 + e], acc[e]);
            }
            loadw(wA, (hd + 8) & (HALF - 1));
            {
                float4 xq = *(const float4*)(xrow + ((((dd >> 2) + 1) ^ l7) << 2));
#pragma unroll
                for (int e = 0; e < 8; ++e) acc[e] = fmaf(xq.x, wB[0 * 8 + e], acc[e]);
#pragma unroll
                for (int e = 0; e < 8; ++e) acc[e] = fmaf(xq.y, wB[1 * 8 + e], acc[e]);
#pragma unroll
                for (int e = 0; e < 8; ++e) acc[e] = fmaf(xq.z, wB[2 * 8 + e], acc[e]);
#pragma unroll
                for (int e = 0; e < 8; ++e) acc[e] = fmaf(xq.w, wB[3 * 8 + e], acc[e]);
            }
        }
    }

    // ---- cross-half reduction via LDS (reuse xs[0]: need 16 KB, have 32 KB)
    __syncthreads();
    float* red = &xs[0][0][0];     // [g][tok][e] = g*512 + tok*8 + e
    if (h == 1) {
#pragma unroll
        for (int e = 0; e < 8; ++e) red[g * 512 + lane * 8 + e] = acc[e];
    }
    __syncthreads();
    if (h == 0) {
        float sc[8];
#pragma unroll
        for (int e = 0; e < 8; ++e) {
            float v = acc[e] + red[g * 512 + lane * 8 + e];
            sc[e] = 1.f / (1.f + expf(-v)) + gb[e0 + e];
        }
        float* so = scores + (size_t)(tok0 + lane) * NE + e0;
        float4 v0 = {sc[0], sc[1], sc[2], sc[3]};
        float4 v1 = {sc[4], sc[5], sc[6], sc[7]};
        ((float4*)so)[0] = v0;
        ((float4*)so)[1] = v1;
    }
}

// ---------- kernel 2: top-8 + normalize (verified tie-break: ties -> lower index) ----------
__global__ __launch_bounds__(256) void topk_kernel(const float* __restrict__ scores,
                                                   float* __restrict__ out) {
    const int tid = threadIdx.x;
    const int t   = blockIdx.x * 64 + (tid >> 2);
    const int q   = tid & 3;
    float v[16];
    const float4* sp = (const float4*)(scores + (size_t)t * NE + q * 16);
    float4 a = sp[0], b = sp[1], c = sp[2], d = sp[3];
    v[0] = a.x;  v[1] = a.y;  v[2] = a.z;  v[3] = a.w;
    v[4] = b.x;  v[5] = b.y;  v[6] = b.z;  v[7] = b.w;
    v[8] = c.x;  v[9] = c.y;  v[10] = c.z; v[11] = c.w;
    v[12] = d.x; v[13] = d.y; v[14] = d.z; v[15] = d.w;

    float kv[TK]; int ki[TK];
#pragma unroll
    for (int k = 0; k < TK; ++k) {
        float bv = v[0]; int bi = q * 16;
#pragma unroll
        for (int j = 1; j < 16; ++j) {
            bool gt = v[j] > bv;
            bv = gt ? v[j] : bv;
            bi = gt ? (q * 16 + j) : bi;
        }
#pragma unroll
        for (int off = 1; off < 4; off <<= 1) {
            float ov = __shfl_xor(bv, off);
            int   oi = __shfl_xor(bi, off);
            bool take = (ov > bv) || (ov == bv && oi < bi);
            bv = take ? ov : bv;
            bi = take ? oi : bi;
        }
        int lj = bi - q * 16;
#pragma unroll
        for (int j = 0; j < 16; ++j) v[j] = (j == lj) ? -3e38f : v[j];
        kv[k] = bv; ki[k] = bi;
    }

    if (q == 0) {
        float s = 0.f;
#pragma unroll
        for (int k = 0; k < TK; ++k) s += kv[k];
        float inv = 1.f / s;
        float* ow = out + (size_t)t * TK;
        float* oi = out + OUT_I_OFF + (size_t)t * TK;
#pragma unroll
        for (int k = 0; k < TK; ++k) {
            ow[k] = kv[k] * inv;
            oi[k] = (float)ki[k];
        }
    }
}

extern "C" void kernel_launch(void* const* d_in, const int* in_sizes, int n_in,
                              void* d_out, int out_size, void* d_ws, size_t ws_size,
                              hipStream_t stream) {
    const float* x  = (const float*)d_in[0];
    const float* w  = (const float*)d_in[1];
    const float* gb = (const float*)d_in[2];
    float* out    = (float*)d_out;
    float* scores = out + OUT_S_OFF;
    float* wtbuf  = (float*)d_ws;
    (void)in_sizes; (void)n_in; (void)out_size;

    const bool use_wt = ws_size >= (size_t)NE * D_DIM * sizeof(float);
    if (use_wt) {
        wtrans_kernel<<<dim3(128), dim3(256), 0, stream>>>(w, wtbuf);
        gate_gemm<true><<<dim3(NTOK / TOKB), dim3(GT), 0, stream>>>(x, w, wtbuf, gb, scores);
    } else {
        gate_gemm<false><<<dim3(NTOK / TOKB), dim3(GT), 0, stream>>>(x, w, wtbuf, gb, scores);
    }
    topk_kernel<<<dim3(NTOK / 64), dim3(256), 0, stream>>>(scores, out);
}